// Round 14
// baseline (1212.016 us; speedup 1.0000x reference)
//
#include <hip/hip_runtime.h>
#include <math.h>

#define Nn 50000
#define Npad 50048
#define Ee 800000
#define FIN 128
#define HIDd 64
#define NH 4
#define HD 256
#define NEG 0.2f
#define BEPS 1e-5f

typedef __attribute__((ext_vector_type(8))) short short8;
typedef __attribute__((ext_vector_type(4))) float f32x4;
typedef unsigned int uint;
typedef unsigned short ushort;

static __device__ __forceinline__ float lrelu(float x) { return x > 0.f ? x : NEG * x; }
static __device__ __forceinline__ float bf2f(ushort x) {
  return __uint_as_float(((uint)x) << 16);
}
static __device__ __forceinline__ ushort f2bf(float f) {
  uint u = __float_as_uint(f);
  return (ushort)((u + 0x7FFF + ((u >> 16) & 1)) >> 16);
}

// ---------------- utility fills ----------------
__global__ void fill_kernel(float* __restrict__ p, float v, int n) {
  int i = blockIdx.x * 256 + threadIdx.x;
  if (i < n) p[i] = v;
}

__global__ void filli_kernel(int* __restrict__ p, int v, int n) {
  int i = blockIdx.x * 256 + threadIdx.x;
  if (i < n) p[i] = v;
}

// ---------------- CSR build (edge_index is layer-invariant: build once) ----------------
__global__ void hist_kernel(const int* __restrict__ dst, int* __restrict__ deg) {
  int i = blockIdx.x * 256 + threadIdx.x;
  if (i < Ee) atomicAdd(&deg[dst[i]], 1);
}

// one block: exclusive scan of deg -> rowstart AND cursor
__global__ __launch_bounds__(1024) void scan_kernel(const int* __restrict__ deg,
                                                    int* __restrict__ rowstart,
                                                    int* __restrict__ cursor) {
  __shared__ int ts[1024];
  const int tid = threadIdx.x;
  const int CH = (Nn + 1023) / 1024;
  const int base = tid * CH;
  int s = 0;
  for (int j = 0; j < CH; j++) {
    int idx = base + j;
    if (idx < Nn) s += deg[idx];
  }
  ts[tid] = s;
  __syncthreads();
  for (int off = 1; off < 1024; off <<= 1) {
    int v = (tid >= off) ? ts[tid - off] : 0;
    __syncthreads();
    ts[tid] += v;
    __syncthreads();
  }
  int run = (tid == 0) ? 0 : ts[tid - 1];
  for (int j = 0; j < CH; j++) {
    int idx = base + j;
    if (idx < Nn) {
      rowstart[idx] = run;
      cursor[idx] = run;
      run += deg[idx];
      if (idx == Nn - 1) rowstart[Nn] = run;
    }
  }
}

__global__ void elist_fill_kernel(const int* __restrict__ src, const int* __restrict__ dst,
                                  int* __restrict__ cursor, int* __restrict__ elist) {
  int i = blockIdx.x * 256 + threadIdx.x;
  if (i >= Ee + Nn) return;
  int s, d;
  if (i < Ee) { s = src[i]; d = dst[i]; } else { s = d = i - Ee; }
  int pos = atomicAdd(&cursor[d], 1);
  elist[pos] = s;
}

// ---------------- bf16 conversions / weight swizzles ----------------
__global__ void cvt_bf16_kernel(const float* __restrict__ in, ushort* __restrict__ out, int n) {
  int i = blockIdx.x * 256 + threadIdx.x;
  if (i < n) out[i] = f2bf(in[i]);
}

// W[K,256] -> B-frag-major
__global__ void wfrag_kernel(const float* __restrict__ W, ushort* __restrict__ Wf, int K) {
  int idx = blockIdx.x * 256 + threadIdx.x;
  int total = (K >> 5) * 16 * 64 * 8;
  if (idx >= total) return;
  int j = idx & 7, lane = (idx >> 3) & 63, t = (idx >> 9) & 15, kc = idx >> 13;
  int n = t * 16 + (lane & 15);
  int k = kc * 32 + ((lane >> 4) << 3) + j;
  Wf[idx] = f2bf(W[k * 256 + n]);
}

// ---------------- MFMA GEMM + fused alpha epilogue; C node-major [row][256] ----------------
__global__ __launch_bounds__(256) void gemm_mfma_kernel(
    const ushort* __restrict__ A, const ushort* __restrict__ Bf, ushort* __restrict__ C, int K,
    const float* __restrict__ a_s, const float* __restrict__ a_d,
    float* __restrict__ asrc, float* __restrict__ adst) {
  const int tid = threadIdx.x;
  const int w = tid >> 6, lane = tid & 63;
  const int q = lane >> 4, nn = lane & 15;
  const int m0 = blockIdx.x * 128 + w * 32;
  const int cb = blockIdx.y;
  f32x4 acc[2][8];
#pragma unroll
  for (int tm = 0; tm < 2; tm++)
#pragma unroll
    for (int t = 0; t < 8; t++) acc[tm][t] = (f32x4){0.f, 0.f, 0.f, 0.f};
  const int nkc = K >> 5;
  for (int kc = 0; kc < nkc; kc++) {
    short8 a0 = *(const short8*)(A + (size_t)(m0 + nn) * K + kc * 32 + q * 8);
    short8 a1 = *(const short8*)(A + (size_t)(m0 + 16 + nn) * K + kc * 32 + q * 8);
#pragma unroll
    for (int t = 0; t < 8; t++) {
      short8 b = *(const short8*)(Bf + ((size_t)((kc * 16 + cb * 8 + t) * 64 + lane)) * 8);
      acc[0][t] = __builtin_amdgcn_mfma_f32_16x16x32_bf16(a0, b, acc[0][t], 0, 0, 0);
      acc[1][t] = __builtin_amdgcn_mfma_f32_16x16x32_bf16(a1, b, acc[1][t], 0, 0, 0);
    }
  }
  float asv[8], adv[8];
#pragma unroll
  for (int t = 0; t < 8; t++) {
    int head = 2 * cb + (t >> 2);
    int dim = (t & 3) * 16 + nn;
    asv[t] = a_s[head * 64 + dim];
    adv[t] = a_d[head * 64 + dim];
  }
#pragma unroll
  for (int tm = 0; tm < 2; tm++) {
    float ps[2][4] = {{0.f, 0.f, 0.f, 0.f}, {0.f, 0.f, 0.f, 0.f}};
    float pd[2][4] = {{0.f, 0.f, 0.f, 0.f}, {0.f, 0.f, 0.f, 0.f}};
#pragma unroll
    for (int t = 0; t < 8; t++) {
      int hp = t >> 2;
#pragma unroll
      for (int r = 0; r < 4; r++) {
        float v = acc[tm][t][r];
        int row = m0 + tm * 16 + q * 4 + r;
        C[(size_t)row * 256 + cb * 128 + t * 16 + nn] = f2bf(v);
        ps[hp][r] = fmaf(v, asv[t], ps[hp][r]);
        pd[hp][r] = fmaf(v, adv[t], pd[hp][r]);
      }
    }
#pragma unroll
    for (int hp = 0; hp < 2; hp++)
#pragma unroll
      for (int r = 0; r < 4; r++) {
        float s = ps[hp][r], d2 = pd[hp][r];
        s += __shfl_xor(s, 1); s += __shfl_xor(s, 2);
        s += __shfl_xor(s, 4); s += __shfl_xor(s, 8);
        d2 += __shfl_xor(d2, 1); d2 += __shfl_xor(d2, 2);
        d2 += __shfl_xor(d2, 4); d2 += __shfl_xor(d2, 8);
        if (nn == 0) {
          int row = m0 + tm * 16 + q * 4 + r;
          asrc[row * 4 + 2 * cb + hp] = s;
          adst[row * 4 + 2 * cb + hp] = d2;
        }
      }
  }
}

// ---------------- gather v7 (round-11 verified best): 8-deep, inline exp, masked tail ----
__global__ __launch_bounds__(256) void gat_gather_kernel(
    const int* __restrict__ elist, const int* __restrict__ rowstart,
    const ushort* __restrict__ h, const float* __restrict__ asrc,
    const float* __restrict__ adst, const float* __restrict__ bias,
    ushort* __restrict__ aggb, float* __restrict__ h2, int concat) {
  const int n = blockIdx.x * 4 + (threadIdx.x >> 6);
  const int lane = threadIdx.x & 63;
  const int hh = lane >> 4;
  const int start = rowstart[n], end = rowstart[n + 1];
  const float adstv = adst[n * 4 + hh];
  const ushort* hcol = h + lane * 4;
  float4 acc = make_float4(0.f, 0.f, 0.f, 0.f);
  float den = 0.f;
  int j = start;
  const int jend = start + ((end - start) & ~7);
  for (; j < jend; j += 8) {
    int ss[8];
    float ww[8];
    ushort4 vv[8];
#pragma unroll
    for (int k = 0; k < 8; k++) ss[k] = elist[j + k];
#pragma unroll
    for (int k = 0; k < 8; k++) vv[k] = *(const ushort4*)(hcol + (size_t)ss[k] * HD);
#pragma unroll
    for (int k = 0; k < 8; k++) ww[k] = __expf(lrelu(asrc[ss[k] * 4 + hh] + adstv));
#pragma unroll
    for (int k = 0; k < 8; k++) {
      den += ww[k];
      acc.x = fmaf(ww[k], bf2f(vv[k].x), acc.x);
      acc.y = fmaf(ww[k], bf2f(vv[k].y), acc.y);
      acc.z = fmaf(ww[k], bf2f(vv[k].z), acc.z);
      acc.w = fmaf(ww[k], bf2f(vv[k].w), acc.w);
    }
  }
  if (j < end) {
    const int cnt = end - j;  // 1..7
    int ss[8];
    float ww[8];
    ushort4 vv[8];
#pragma unroll
    for (int k = 0; k < 8; k++) ss[k] = elist[k < cnt ? j + k : j];
#pragma unroll
    for (int k = 0; k < 8; k++) vv[k] = *(const ushort4*)(hcol + (size_t)ss[k] * HD);
#pragma unroll
    for (int k = 0; k < 8; k++) {
      float e = __expf(lrelu(asrc[ss[k] * 4 + hh] + adstv));
      ww[k] = (k < cnt) ? e : 0.f;
    }
#pragma unroll
    for (int k = 0; k < 8; k++) {
      den += ww[k];
      acc.x = fmaf(ww[k], bf2f(vv[k].x), acc.x);
      acc.y = fmaf(ww[k], bf2f(vv[k].y), acc.y);
      acc.z = fmaf(ww[k], bf2f(vv[k].z), acc.z);
      acc.w = fmaf(ww[k], bf2f(vv[k].w), acc.w);
    }
  }
  float inv = 1.f / den;
  float o0 = acc.x * inv, o1 = acc.y * inv, o2 = acc.z * inv, o3 = acc.w * inv;
  if (concat) {
    float4 bv = *(const float4*)(bias + lane * 4);
    ushort4 ov;
    ov.x = f2bf(o0 + bv.x); ov.y = f2bf(o1 + bv.y);
    ov.z = f2bf(o2 + bv.z); ov.w = f2bf(o3 + bv.w);
    *(ushort4*)(aggb + (size_t)n * HD + lane * 4) = ov;
  } else {
    // head-mean: heads live in 16-lane groups (lane, lane^16, lane^32)
    o0 += __shfl_xor(o0, 16); o0 += __shfl_xor(o0, 32);
    o1 += __shfl_xor(o1, 16); o1 += __shfl_xor(o1, 32);
    o2 += __shfl_xor(o2, 16); o2 += __shfl_xor(o2, 32);
    o3 += __shfl_xor(o3, 16); o3 += __shfl_xor(o3, 32);
    if (lane < 16) {
      float4 bv = *(const float4*)(bias + lane * 4);
      *(float4*)(h2 + (size_t)n * 64 + lane * 4) =
          make_float4(o0 * 0.25f + bv.x, o1 * 0.25f + bv.y,
                      o2 * 0.25f + bv.z, o3 * 0.25f + bv.w);
    }
  }
}

// ---------------- BatchNorm (separate kernels — known good) ----------------
__global__ void bn_stats_bf16_kernel(const ushort* __restrict__ x, float* __restrict__ stats,
                                     int nrows, int C) {
  int r0 = blockIdx.x * 512;
  int tpc = 256 / C;
  int c = threadIdx.x % C;
  int ro = threadIdx.x / C;
  int rend = min(r0 + 512, nrows);
  float s = 0.f, s2 = 0.f;
  for (int r = r0 + ro; r < rend; r += tpc) {
    float v = bf2f(x[(size_t)r * C + c]);
    s += v; s2 += v * v;
  }
  atomicAdd(&stats[c], s);
  atomicAdd(&stats[C + c], s2);
}

__global__ void bn_stats_kernel(const float* __restrict__ x, float* __restrict__ stats,
                                int nrows, int C) {
  int r0 = blockIdx.x * 512;
  int tpc = 256 / C;
  int c = threadIdx.x % C;
  int ro = threadIdx.x / C;
  int rend = min(r0 + 512, nrows);
  float s = 0.f, s2 = 0.f;
  for (int r = r0 + ro; r < rend; r += tpc) {
    float v = x[(size_t)r * C + c];
    s += v; s2 += v * v;
  }
  atomicAdd(&stats[c], s);
  atomicAdd(&stats[C + c], s2);
}

// in-place bf16 BN (+lrelu)
__global__ void bn_apply_inplace_kernel(ushort* __restrict__ x, const float* __restrict__ stats,
                                        const float* __restrict__ g, const float* __restrict__ be,
                                        int C) {
  int i = blockIdx.x * 256 + threadIdx.x;
  if (i >= Nn * C) return;
  int c = i % C;
  float mu = stats[c] * (1.f / Nn);
  float var = stats[C + c] * (1.f / Nn) - mu * mu;
  float y = (bf2f(x[i]) - mu) * rsqrtf(var + BEPS) * g[c] + be[c];
  x[i] = f2bf(lrelu(y));
}

// fp32-in bf16-out BN (no lrelu) — layer 2
__global__ void bn_apply_bf16_kernel(const float* __restrict__ x, const float* __restrict__ stats,
                                     const float* __restrict__ g, const float* __restrict__ be,
                                     ushort* __restrict__ outb, int C) {
  int i = blockIdx.x * 256 + threadIdx.x;
  if (i >= Nn * C) return;
  int c = i % C;
  float mu = stats[c] * (1.f / Nn);
  float var = stats[C + c] * (1.f / Nn) - mu * mu;
  float y = (x[i] - mu) * rsqrtf(var + BEPS) * g[c] + be[c];
  outb[i] = f2bf(y);
}

// ---------------- edge-MLP weight swizzles ----------------
__global__ void w1frag_kernel(const float* __restrict__ Wm1, ushort* __restrict__ W1f) {
  int idx = blockIdx.x * 256 + threadIdx.x;
  if (idx >= 7 * 8 * 64 * 8) return;
  int j = idx & 7, lane = (idx >> 3) & 63, tile = (idx >> 9) & 7, chunk = idx >> 12;
  int n = tile * 16 + (lane & 15);
  int k = chunk * 32 + (lane >> 4) * 8 + j;
  W1f[idx] = (k < 193) ? f2bf(Wm1[k * 128 + n]) : (ushort)0;
}

__global__ void w2frag_kernel(const float* __restrict__ Wm2, ushort* __restrict__ W2f) {
  int idx = blockIdx.x * 256 + threadIdx.x;
  if (idx >= 4 * 4 * 64 * 8) return;
  int j = idx & 7, lane = (idx >> 3) & 63, tile = (idx >> 9) & 3, chunk = idx >> 11;
  int n = tile * 16 + (lane & 15);
  int k = chunk * 32 + (lane >> 4) * 8 + j;
  W2f[idx] = f2bf(Wm2[k * 64 + n]);
}

// ---------------- Edge MLP v3: sequential 16-edge groups (half regs, 2x occupancy) ------
static __device__ __forceinline__ short8 absdiff8(short8 a, short8 b) {
  short8 r;
#pragma unroll
  for (int j = 0; j < 8; j++) {
    float d = bf2f((ushort)a[j]) - bf2f((ushort)b[j]);
    r[j] = (short)(ushort)((__float_as_uint(d) & 0x7fffffffu) >> 16);
  }
  return r;
}

#define MLP1_STEP1(c, ax)                                                              \
  {                                                                                    \
    short8 _a = (ax);                                                                  \
    const uint4* bp = (const uint4*)W1f + (c) * 512 + lane;                            \
    _Pragma("unroll") for (int t = 0; t < 8; t++) {                                    \
      uint4 braw = bp[t * 64];                                                         \
      short8 b = *(short8*)&braw;                                                      \
      acc[t] = __builtin_amdgcn_mfma_f32_16x16x32_bf16(_a, b, acc[t], 0, 0, 0);        \
    }                                                                                  \
  }

__global__ __launch_bounds__(256) void edge_mlp_mfma_kernel(
    const ushort* __restrict__ hb, const int* __restrict__ src, const int* __restrict__ dst,
    const float* __restrict__ eattr, const ushort* __restrict__ W1f,
    const ushort* __restrict__ W2f, const float* __restrict__ bm1,
    const float* __restrict__ bm2, const float* __restrict__ Wm3,
    const float* __restrict__ bm3, float* __restrict__ out) {
  __shared__ ushort t1s[4][16 * 136];  // per-wave private: no barriers needed
  const int tid = threadIdx.x;
  const int w = tid >> 6, lane = tid & 63;
  const int q = lane >> 4, nn = lane & 15;

  float bm1v[8];
#pragma unroll
  for (int t = 0; t < 8; t++) bm1v[t] = bm1[t * 16 + nn];
  float bm2v[4], w3v[4];
#pragma unroll
  for (int t = 0; t < 4; t++) { bm2v[t] = bm2[t * 16 + nn]; w3v[t] = Wm3[t * 16 + nn]; }
  const float bm3v = bm3[0];

  const int base = blockIdx.x * 128 + w * 32;
  ushort* myt1 = t1s[w];

#pragma unroll 1
  for (int g = 0; g < 2; g++) {
    const int e = base + g * 16 + nn;
    const int s = src[e], d = dst[e];
    const float at = eattr[e];
    short8 hsa = *(const short8*)(hb + s * 64 + q * 8);
    short8 hsb = *(const short8*)(hb + s * 64 + 32 + q * 8);
    short8 hda = *(const short8*)(hb + d * 64 + q * 8);
    short8 hdb = *(const short8*)(hb + d * 64 + 32 + q * 8);

    f32x4 acc[8];
#pragma unroll
    for (int t = 0; t < 8; t++) acc[t] = (f32x4){0.f, 0.f, 0.f, 0.f};

    short8 a6 = 0;
    if (q == 0) a6[0] = (short)f2bf(at);

    MLP1_STEP1(0, hsa)
    MLP1_STEP1(1, hsb)
    MLP1_STEP1(2, hda)
    MLP1_STEP1(3, hdb)
    MLP1_STEP1(4, absdiff8(hsa, hda))
    MLP1_STEP1(5, absdiff8(hsb, hdb))
    MLP1_STEP1(6, a6)

    // t1 (C-layout row=q*4+r edge, col=t*16+nn) -> LDS bf16, +bias+lrelu
#pragma unroll
    for (int t = 0; t < 8; t++)
#pragma unroll
      for (int r = 0; r < 4; r++)
        myt1[(q * 4 + r) * 136 + t * 16 + nn] = f2bf(lrelu(acc[t][r] + bm1v[t]));

    f32x4 acc2[4];
#pragma unroll
    for (int t = 0; t < 4; t++) acc2[t] = (f32x4){0.f, 0.f, 0.f, 0.f};
#pragma unroll
    for (int c2 = 0; c2 < 4; c2++) {
      short8 a = *(short8*)&myt1[nn * 136 + c2 * 32 + q * 8];
#pragma unroll
      for (int t = 0; t < 4; t++) {
        short8 b = *(const short8*)(W2f + ((size_t)(c2 * 4 + t) * 64 + lane) * 8);
        acc2[t] = __builtin_amdgcn_mfma_f32_16x16x32_bf16(a, b, acc2[t], 0, 0, 0);
      }
    }
#pragma unroll
    for (int r = 0; r < 4; r++) {
      float sum = 0.f;
#pragma unroll
      for (int t = 0; t < 4; t++) sum += lrelu(acc2[t][r] + bm2v[t]) * w3v[t];
      sum += __shfl_xor(sum, 1);
      sum += __shfl_xor(sum, 2);
      sum += __shfl_xor(sum, 4);
      sum += __shfl_xor(sum, 8);
      if (nn == 0) out[base + g * 16 + q * 4 + r] = sum + bm3v;
    }
  }
}

// ---------------- orchestration ----------------
extern "C" void kernel_launch(void* const* d_in, const int* in_sizes, int n_in,
                              void* d_out, int out_size, void* d_ws, size_t ws_size,
                              hipStream_t stream) {
  const float* x    = (const float*)d_in[0];
  const int*   ei   = (const int*)d_in[1];
  const float* eatt = (const float*)d_in[2];
  const float* W0 = (const float*)d_in[3];
  const float* as0 = (const float*)d_in[4];
  const float* ad0 = (const float*)d_in[5];
  const float* b0 = (const float*)d_in[6];
  const float* W1 = (const float*)d_in[7];
  const float* as1 = (const float*)d_in[8];
  const float* ad1 = (const float*)d_in[9];
  const float* b1 = (const float*)d_in[10];
  const float* W2 = (const float*)d_in[11];
  const float* as2 = (const float*)d_in[12];
  const float* ad2 = (const float*)d_in[13];
  const float* b2 = (const float*)d_in[14];
  const float* g0 = (const float*)d_in[15];
  const float* be0 = (const float*)d_in[16];
  const float* g1 = (const float*)d_in[17];
  const float* be1 = (const float*)d_in[18];
  const float* g2 = (const float*)d_in[19];
  const float* be2 = (const float*)d_in[20];
  const float* Wm1 = (const float*)d_in[21];
  const float* bm1 = (const float*)d_in[22];
  const float* Wm2 = (const float*)d_in[23];
  const float* bm2 = (const float*)d_in[24];
  const float* Wm3 = (const float*)d_in[25];
  const float* bm3 = (const float*)d_in[26];
  const int* src = ei;
  const int* dst = ei + Ee;
  float* out = (float*)d_out;

  // ---- workspace layout ----
  char* w = (char*)d_ws;
  ushort* xb   = (ushort*)w;                                  // Npad*128 bf16 (layer-0 A)
  ushort* hB   = (ushort*)(w + (size_t)Npad * 256 * 4);       // node-major [Npad][256] bf16
  ushort* aggb = (ushort*)(w + (size_t)Npad * 256 * 6);       // Npad*256 bf16 (post-gather/BN A)
  float*  h2   = (float*)aggb;                                // alias (layer-2 only): Nn*64 fp32
  ushort* hb2  = (ushort*)(w + (size_t)Npad * 256 * 6 + (size_t)Nn * 64 * 4);  // Nn*64 bf16
  float*  asrc = (float*)(w + (size_t)Npad * 256 * 8);        // Npad*4
  float*  adst = asrc + (size_t)Npad * 4;                     // Npad*4
  float*  stats = adst + (size_t)Npad * 4;                    // 512
  int* deg      = (int*)(stats + 512);                        // Nn
  int* rowstart = deg + Nn;                                   // Nn+16
  int* cursor   = rowstart + Nn + 16;                         // Nn
  int* elist    = cursor + Nn;                                // Ee+Nn
  ushort* W0f  = (ushort*)(elist + Ee + Nn);                  // 32768
  ushort* W1gf = W0f + 32768;                                 // 65536
  ushort* W2gf = W1gf + 65536;                                // 65536
  ushort* eW1f = W2gf + 65536;                                // 28672
  ushort* eW2f = eW1f + 28672;                                // 8192

  // ---- CSR build (once; edge_index identical for all 3 layers) ----
  filli_kernel<<<(Nn + 255) / 256, 256, 0, stream>>>(deg, 1, Nn);  // self loops
  hist_kernel<<<(Ee + 255) / 256, 256, 0, stream>>>(dst, deg);
  scan_kernel<<<1, 1024, 0, stream>>>(deg, rowstart, cursor);
  elist_fill_kernel<<<(Ee + Nn + 255) / 256, 256, 0, stream>>>(src, dst, cursor, elist);

  // ---- weight swizzles (once) ----
  wfrag_kernel<<<(32768 + 255) / 256, 256, 0, stream>>>(W0, W0f, FIN);
  wfrag_kernel<<<(65536 + 255) / 256, 256, 0, stream>>>(W1, W1gf, HD);
  wfrag_kernel<<<(65536 + 255) / 256, 256, 0, stream>>>(W2, W2gf, HD);
  w1frag_kernel<<<(7 * 8 * 64 * 8 + 255) / 256, 256, 0, stream>>>(Wm1, eW1f);
  w2frag_kernel<<<(4 * 4 * 64 * 8 + 255) / 256, 256, 0, stream>>>(Wm2, eW2f);

  auto gat = [&](const ushort* Ab, const ushort* Wf, int K, const float* a_s,
                 const float* a_d, const float* bias, bool concat) {
    gemm_mfma_kernel<<<dim3(Npad / 128, 2), 256, 0, stream>>>(Ab, Wf, hB, K, a_s, a_d,
                                                              asrc, adst);
    gat_gather_kernel<<<Nn / 4, 256, 0, stream>>>(elist, rowstart, hB, asrc, adst, bias,
                                                  aggb, h2, concat ? 1 : 0);
  };

  // Layer 0
  cvt_bf16_kernel<<<(Nn * FIN + 255) / 256, 256, 0, stream>>>(x, xb, Nn * FIN);
  gat(xb, W0f, FIN, as0, ad0, b0, true);
  fill_kernel<<<2, 256, 0, stream>>>(stats, 0.f, 512);
  bn_stats_bf16_kernel<<<(Nn + 511) / 512, 256, 0, stream>>>(aggb, stats, Nn, HD);
  bn_apply_inplace_kernel<<<(Nn * HD + 255) / 256, 256, 0, stream>>>(aggb, stats, g0, be0, HD);
  // Layer 1
  gat(aggb, W1gf, HD, as1, ad1, b1, true);
  fill_kernel<<<2, 256, 0, stream>>>(stats, 0.f, 512);
  bn_stats_bf16_kernel<<<(Nn + 511) / 512, 256, 0, stream>>>(aggb, stats, Nn, HD);
  bn_apply_inplace_kernel<<<(Nn * HD + 255) / 256, 256, 0, stream>>>(aggb, stats, g1, be1, HD);
  // Layer 2 (concat=False; head-mean + b2 fused into gather -> h2 fp32)
  gat(aggb, W2gf, HD, as2, ad2, b2, false);
  fill_kernel<<<1, 256, 0, stream>>>(stats, 0.f, 128);
  bn_stats_kernel<<<(Nn + 511) / 512, 256, 0, stream>>>(h2, stats, Nn, HIDd);
  bn_apply_bf16_kernel<<<(Nn * HIDd + 255) / 256, 256, 0, stream>>>(h2, stats, g2, be2, hb2,
                                                                    HIDd);
  // ---- Edge MLP (MFMA bf16, v3 sequential groups) ----
  edge_mlp_mfma_kernel<<<Ee / 128, 256, 0, stream>>>(hb2, src, dst, eatt, eW1f, eW2f, bm1, bm2,
                                                     Wm3, bm3, out);
}

// Round 15
// 1122.657 us; speedup vs baseline: 1.0796x; 1.0796x over previous
//
#include <hip/hip_runtime.h>
#include <math.h>

#define Nn 50000
#define Npad 50048
#define Ee 800000
#define FIN 128
#define HIDd 64
#define NH 4
#define HD 256
#define NEG 0.2f
#define BEPS 1e-5f

typedef __attribute__((ext_vector_type(8))) short short8;
typedef __attribute__((ext_vector_type(4))) float f32x4;
typedef unsigned int uint;
typedef unsigned short ushort;

static __device__ __forceinline__ float lrelu(float x) { return x > 0.f ? x : NEG * x; }
static __device__ __forceinline__ float bf2f(ushort x) {
  return __uint_as_float(((uint)x) << 16);
}
static __device__ __forceinline__ ushort f2bf(float f) {
  uint u = __float_as_uint(f);
  return (ushort)((u + 0x7FFF + ((u >> 16) & 1)) >> 16);
}

// ---------------- utility fills ----------------
__global__ void fill_kernel(float* __restrict__ p, float v, int n) {
  int i = blockIdx.x * 256 + threadIdx.x;
  if (i < n) p[i] = v;
}

__global__ void filli_kernel(int* __restrict__ p, int v, int n) {
  int i = blockIdx.x * 256 + threadIdx.x;
  if (i < n) p[i] = v;
}

// ---------------- CSR build (edge_index is layer-invariant: build once) ----------------
__global__ void hist_kernel(const int* __restrict__ dst, int* __restrict__ deg) {
  int i = blockIdx.x * 256 + threadIdx.x;
  if (i < Ee) atomicAdd(&deg[dst[i]], 1);
}

// one block: exclusive scan of deg -> rowstart AND cursor
__global__ __launch_bounds__(1024) void scan_kernel(const int* __restrict__ deg,
                                                    int* __restrict__ rowstart,
                                                    int* __restrict__ cursor) {
  __shared__ int ts[1024];
  const int tid = threadIdx.x;
  const int CH = (Nn + 1023) / 1024;
  const int base = tid * CH;
  int s = 0;
  for (int j = 0; j < CH; j++) {
    int idx = base + j;
    if (idx < Nn) s += deg[idx];
  }
  ts[tid] = s;
  __syncthreads();
  for (int off = 1; off < 1024; off <<= 1) {
    int v = (tid >= off) ? ts[tid - off] : 0;
    __syncthreads();
    ts[tid] += v;
    __syncthreads();
  }
  int run = (tid == 0) ? 0 : ts[tid - 1];
  for (int j = 0; j < CH; j++) {
    int idx = base + j;
    if (idx < Nn) {
      rowstart[idx] = run;
      cursor[idx] = run;
      run += deg[idx];
      if (idx == Nn - 1) rowstart[Nn] = run;
    }
  }
}

__global__ void elist_fill_kernel(const int* __restrict__ src, const int* __restrict__ dst,
                                  int* __restrict__ cursor, int* __restrict__ elist) {
  int i = blockIdx.x * 256 + threadIdx.x;
  if (i >= Ee + Nn) return;
  int s, d;
  if (i < Ee) { s = src[i]; d = dst[i]; } else { s = d = i - Ee; }
  int pos = atomicAdd(&cursor[d], 1);
  elist[pos] = s;
}

// ---------------- bf16 conversions / weight swizzles ----------------
__global__ void cvt_bf16_kernel(const float* __restrict__ in, ushort* __restrict__ out, int n) {
  int i = blockIdx.x * 256 + threadIdx.x;
  if (i < n) out[i] = f2bf(in[i]);
}

// W[K,256] -> B-frag-major
__global__ void wfrag_kernel(const float* __restrict__ W, ushort* __restrict__ Wf, int K) {
  int idx = blockIdx.x * 256 + threadIdx.x;
  int total = (K >> 5) * 16 * 64 * 8;
  if (idx >= total) return;
  int j = idx & 7, lane = (idx >> 3) & 63, t = (idx >> 9) & 15, kc = idx >> 13;
  int n = t * 16 + (lane & 15);
  int k = kc * 32 + ((lane >> 4) << 3) + j;
  Wf[idx] = f2bf(W[k * 256 + n]);
}

// ---------------- MFMA GEMM + fused alpha epilogue; C node-major [row][256] ----------------
__global__ __launch_bounds__(256) void gemm_mfma_kernel(
    const ushort* __restrict__ A, const ushort* __restrict__ Bf, ushort* __restrict__ C, int K,
    const float* __restrict__ a_s, const float* __restrict__ a_d,
    float* __restrict__ asrc, float* __restrict__ adst) {
  const int tid = threadIdx.x;
  const int w = tid >> 6, lane = tid & 63;
  const int q = lane >> 4, nn = lane & 15;
  const int m0 = blockIdx.x * 128 + w * 32;
  const int cb = blockIdx.y;
  f32x4 acc[2][8];
#pragma unroll
  for (int tm = 0; tm < 2; tm++)
#pragma unroll
    for (int t = 0; t < 8; t++) acc[tm][t] = (f32x4){0.f, 0.f, 0.f, 0.f};
  const int nkc = K >> 5;
  for (int kc = 0; kc < nkc; kc++) {
    short8 a0 = *(const short8*)(A + (size_t)(m0 + nn) * K + kc * 32 + q * 8);
    short8 a1 = *(const short8*)(A + (size_t)(m0 + 16 + nn) * K + kc * 32 + q * 8);
#pragma unroll
    for (int t = 0; t < 8; t++) {
      short8 b = *(const short8*)(Bf + ((size_t)((kc * 16 + cb * 8 + t) * 64 + lane)) * 8);
      acc[0][t] = __builtin_amdgcn_mfma_f32_16x16x32_bf16(a0, b, acc[0][t], 0, 0, 0);
      acc[1][t] = __builtin_amdgcn_mfma_f32_16x16x32_bf16(a1, b, acc[1][t], 0, 0, 0);
    }
  }
  float asv[8], adv[8];
#pragma unroll
  for (int t = 0; t < 8; t++) {
    int head = 2 * cb + (t >> 2);
    int dim = (t & 3) * 16 + nn;
    asv[t] = a_s[head * 64 + dim];
    adv[t] = a_d[head * 64 + dim];
  }
#pragma unroll
  for (int tm = 0; tm < 2; tm++) {
    float ps[2][4] = {{0.f, 0.f, 0.f, 0.f}, {0.f, 0.f, 0.f, 0.f}};
    float pd[2][4] = {{0.f, 0.f, 0.f, 0.f}, {0.f, 0.f, 0.f, 0.f}};
#pragma unroll
    for (int t = 0; t < 8; t++) {
      int hp = t >> 2;
#pragma unroll
      for (int r = 0; r < 4; r++) {
        float v = acc[tm][t][r];
        int row = m0 + tm * 16 + q * 4 + r;
        C[(size_t)row * 256 + cb * 128 + t * 16 + nn] = f2bf(v);
        ps[hp][r] = fmaf(v, asv[t], ps[hp][r]);
        pd[hp][r] = fmaf(v, adv[t], pd[hp][r]);
      }
    }
#pragma unroll
    for (int hp = 0; hp < 2; hp++)
#pragma unroll
      for (int r = 0; r < 4; r++) {
        float s = ps[hp][r], d2 = pd[hp][r];
        s += __shfl_xor(s, 1); s += __shfl_xor(s, 2);
        s += __shfl_xor(s, 4); s += __shfl_xor(s, 8);
        d2 += __shfl_xor(d2, 1); d2 += __shfl_xor(d2, 2);
        d2 += __shfl_xor(d2, 4); d2 += __shfl_xor(d2, 8);
        if (nn == 0) {
          int row = m0 + tm * 16 + q * 4 + r;
          asrc[row * 4 + 2 * cb + hp] = s;
          adst[row * 4 + 2 * cb + hp] = d2;
        }
      }
  }
}

// ---------------- gather v7 (round-11 verified best): 8-deep, inline exp, masked tail ----
__global__ __launch_bounds__(256) void gat_gather_kernel(
    const int* __restrict__ elist, const int* __restrict__ rowstart,
    const ushort* __restrict__ h, const float* __restrict__ asrc,
    const float* __restrict__ adst, const float* __restrict__ bias,
    ushort* __restrict__ aggb, float* __restrict__ h2, int concat) {
  const int n = blockIdx.x * 4 + (threadIdx.x >> 6);
  const int lane = threadIdx.x & 63;
  const int hh = lane >> 4;
  const int start = rowstart[n], end = rowstart[n + 1];
  const float adstv = adst[n * 4 + hh];
  const ushort* hcol = h + lane * 4;
  float4 acc = make_float4(0.f, 0.f, 0.f, 0.f);
  float den = 0.f;
  int j = start;
  const int jend = start + ((end - start) & ~7);
  for (; j < jend; j += 8) {
    int ss[8];
    float ww[8];
    ushort4 vv[8];
#pragma unroll
    for (int k = 0; k < 8; k++) ss[k] = elist[j + k];
#pragma unroll
    for (int k = 0; k < 8; k++) vv[k] = *(const ushort4*)(hcol + (size_t)ss[k] * HD);
#pragma unroll
    for (int k = 0; k < 8; k++) ww[k] = __expf(lrelu(asrc[ss[k] * 4 + hh] + adstv));
#pragma unroll
    for (int k = 0; k < 8; k++) {
      den += ww[k];
      acc.x = fmaf(ww[k], bf2f(vv[k].x), acc.x);
      acc.y = fmaf(ww[k], bf2f(vv[k].y), acc.y);
      acc.z = fmaf(ww[k], bf2f(vv[k].z), acc.z);
      acc.w = fmaf(ww[k], bf2f(vv[k].w), acc.w);
    }
  }
  if (j < end) {
    const int cnt = end - j;  // 1..7
    int ss[8];
    float ww[8];
    ushort4 vv[8];
#pragma unroll
    for (int k = 0; k < 8; k++) ss[k] = elist[k < cnt ? j + k : j];
#pragma unroll
    for (int k = 0; k < 8; k++) vv[k] = *(const ushort4*)(hcol + (size_t)ss[k] * HD);
#pragma unroll
    for (int k = 0; k < 8; k++) {
      float e = __expf(lrelu(asrc[ss[k] * 4 + hh] + adstv));
      ww[k] = (k < cnt) ? e : 0.f;
    }
#pragma unroll
    for (int k = 0; k < 8; k++) {
      den += ww[k];
      acc.x = fmaf(ww[k], bf2f(vv[k].x), acc.x);
      acc.y = fmaf(ww[k], bf2f(vv[k].y), acc.y);
      acc.z = fmaf(ww[k], bf2f(vv[k].z), acc.z);
      acc.w = fmaf(ww[k], bf2f(vv[k].w), acc.w);
    }
  }
  float inv = 1.f / den;
  float o0 = acc.x * inv, o1 = acc.y * inv, o2 = acc.z * inv, o3 = acc.w * inv;
  if (concat) {
    float4 bv = *(const float4*)(bias + lane * 4);
    ushort4 ov;
    ov.x = f2bf(o0 + bv.x); ov.y = f2bf(o1 + bv.y);
    ov.z = f2bf(o2 + bv.z); ov.w = f2bf(o3 + bv.w);
    *(ushort4*)(aggb + (size_t)n * HD + lane * 4) = ov;
  } else {
    // head-mean: heads live in 16-lane groups (lane, lane^16, lane^32)
    o0 += __shfl_xor(o0, 16); o0 += __shfl_xor(o0, 32);
    o1 += __shfl_xor(o1, 16); o1 += __shfl_xor(o1, 32);
    o2 += __shfl_xor(o2, 16); o2 += __shfl_xor(o2, 32);
    o3 += __shfl_xor(o3, 16); o3 += __shfl_xor(o3, 32);
    if (lane < 16) {
      float4 bv = *(const float4*)(bias + lane * 4);
      *(float4*)(h2 + (size_t)n * 64 + lane * 4) =
          make_float4(o0 * 0.25f + bv.x, o1 * 0.25f + bv.y,
                      o2 * 0.25f + bv.z, o3 * 0.25f + bv.w);
    }
  }
}

// ---------------- BatchNorm (separate kernels — known good) ----------------
__global__ void bn_stats_bf16_kernel(const ushort* __restrict__ x, float* __restrict__ stats,
                                     int nrows, int C) {
  int r0 = blockIdx.x * 512;
  int tpc = 256 / C;
  int c = threadIdx.x % C;
  int ro = threadIdx.x / C;
  int rend = min(r0 + 512, nrows);
  float s = 0.f, s2 = 0.f;
  for (int r = r0 + ro; r < rend; r += tpc) {
    float v = bf2f(x[(size_t)r * C + c]);
    s += v; s2 += v * v;
  }
  atomicAdd(&stats[c], s);
  atomicAdd(&stats[C + c], s2);
}

__global__ void bn_stats_kernel(const float* __restrict__ x, float* __restrict__ stats,
                                int nrows, int C) {
  int r0 = blockIdx.x * 512;
  int tpc = 256 / C;
  int c = threadIdx.x % C;
  int ro = threadIdx.x / C;
  int rend = min(r0 + 512, nrows);
  float s = 0.f, s2 = 0.f;
  for (int r = r0 + ro; r < rend; r += tpc) {
    float v = x[(size_t)r * C + c];
    s += v; s2 += v * v;
  }
  atomicAdd(&stats[c], s);
  atomicAdd(&stats[C + c], s2);
}

// in-place bf16 BN (+lrelu)
__global__ void bn_apply_inplace_kernel(ushort* __restrict__ x, const float* __restrict__ stats,
                                        const float* __restrict__ g, const float* __restrict__ be,
                                        int C) {
  int i = blockIdx.x * 256 + threadIdx.x;
  if (i >= Nn * C) return;
  int c = i % C;
  float mu = stats[c] * (1.f / Nn);
  float var = stats[C + c] * (1.f / Nn) - mu * mu;
  float y = (bf2f(x[i]) - mu) * rsqrtf(var + BEPS) * g[c] + be[c];
  x[i] = f2bf(lrelu(y));
}

// fp32-in bf16-out BN (no lrelu) — layer 2
__global__ void bn_apply_bf16_kernel(const float* __restrict__ x, const float* __restrict__ stats,
                                     const float* __restrict__ g, const float* __restrict__ be,
                                     ushort* __restrict__ outb, int C) {
  int i = blockIdx.x * 256 + threadIdx.x;
  if (i >= Nn * C) return;
  int c = i % C;
  float mu = stats[c] * (1.f / Nn);
  float var = stats[C + c] * (1.f / Nn) - mu * mu;
  float y = (x[i] - mu) * rsqrtf(var + BEPS) * g[c] + be[c];
  outb[i] = f2bf(y);
}

// ---------------- edge-MLP weight swizzles ----------------
__global__ void w1frag_kernel(const float* __restrict__ Wm1, ushort* __restrict__ W1f) {
  int idx = blockIdx.x * 256 + threadIdx.x;
  if (idx >= 7 * 8 * 64 * 8) return;
  int j = idx & 7, lane = (idx >> 3) & 63, tile = (idx >> 9) & 7, chunk = idx >> 12;
  int n = tile * 16 + (lane & 15);
  int k = chunk * 32 + (lane >> 4) * 8 + j;
  W1f[idx] = (k < 193) ? f2bf(Wm1[k * 128 + n]) : (ushort)0;
}

__global__ void w2frag_kernel(const float* __restrict__ Wm2, ushort* __restrict__ W2f) {
  int idx = blockIdx.x * 256 + threadIdx.x;
  if (idx >= 4 * 4 * 64 * 8) return;
  int j = idx & 7, lane = (idx >> 3) & 63, tile = (idx >> 9) & 3, chunk = idx >> 11;
  int n = tile * 16 + (lane & 15);
  int k = chunk * 32 + (lane >> 4) * 8 + j;
  W2f[idx] = f2bf(Wm2[k * 64 + n]);
}

// ---------------- Edge MLP via MFMA ------------------------------------------------------
// NOTE: this straight-line structure (all 8 h-frags up front, biases at top, chunks 0..6,
// per-wave LDS, no barriers) is a verified register-allocation optimum: 80 VGPR + 64 AGPR,
// 31% occ, 158 us. Two restructure attempts (phased loads r9, sequential groups r14) both
// ballooned VGPR (92/196) and regressed 1.5x. Do not restructure without asm evidence.
static __device__ __forceinline__ short8 absdiff8(short8 a, short8 b) {
  short8 r;
#pragma unroll
  for (int j = 0; j < 8; j++) {
    float d = bf2f((ushort)a[j]) - bf2f((ushort)b[j]);
    r[j] = (short)(ushort)((__float_as_uint(d) & 0x7fffffffu) >> 16);
  }
  return r;
}

#define MLP1_STEP(c, e0x, e1x)                                                         \
  {                                                                                    \
    short8 _a0 = (e0x);                                                                \
    short8 _a1 = (e1x);                                                                \
    const uint4* bp = (const uint4*)W1f + (c) * 512 + lane;                            \
    _Pragma("unroll") for (int t = 0; t < 8; t++) {                                    \
      uint4 braw = bp[t * 64];                                                         \
      short8 b = *(short8*)&braw;                                                      \
      acc0[t] = __builtin_amdgcn_mfma_f32_16x16x32_bf16(_a0, b, acc0[t], 0, 0, 0);     \
      acc1[t] = __builtin_amdgcn_mfma_f32_16x16x32_bf16(_a1, b, acc1[t], 0, 0, 0);     \
    }                                                                                  \
  }

__global__ __launch_bounds__(256) void edge_mlp_mfma_kernel(
    const ushort* __restrict__ hb, const int* __restrict__ src, const int* __restrict__ dst,
    const float* __restrict__ eattr, const ushort* __restrict__ W1f,
    const ushort* __restrict__ W2f, const float* __restrict__ bm1,
    const float* __restrict__ bm2, const float* __restrict__ Wm3,
    const float* __restrict__ bm3, float* __restrict__ out) {
  __shared__ ushort t1s[4][16 * 136];  // per-wave private: no barriers needed
  const int tid = threadIdx.x;
  const int w = tid >> 6, lane = tid & 63;
  const int q = lane >> 4, nn = lane & 15;

  float bm1v[8];
#pragma unroll
  for (int t = 0; t < 8; t++) bm1v[t] = bm1[t * 16 + nn];
  float bm2v[4], w3v[4];
#pragma unroll
  for (int t = 0; t < 4; t++) { bm2v[t] = bm2[t * 16 + nn]; w3v[t] = Wm3[t * 16 + nn]; }
  const float bm3v = bm3[0];

  const int base = blockIdx.x * 128 + w * 32;
  const int e0 = base + nn, e1 = base + 16 + nn;
  const int s0 = src[e0], d0 = dst[e0];
  const int s1 = src[e1], d1 = dst[e1];
  const float at0 = eattr[e0], at1 = eattr[e1];

  short8 hs0a = *(const short8*)(hb + s0 * 64 + q * 8);
  short8 hs0b = *(const short8*)(hb + s0 * 64 + 32 + q * 8);
  short8 hd0a = *(const short8*)(hb + d0 * 64 + q * 8);
  short8 hd0b = *(const short8*)(hb + d0 * 64 + 32 + q * 8);
  short8 hs1a = *(const short8*)(hb + s1 * 64 + q * 8);
  short8 hs1b = *(const short8*)(hb + s1 * 64 + 32 + q * 8);
  short8 hd1a = *(const short8*)(hb + d1 * 64 + q * 8);
  short8 hd1b = *(const short8*)(hb + d1 * 64 + 32 + q * 8);

  f32x4 acc0[8], acc1[8];
#pragma unroll
  for (int t = 0; t < 8; t++) {
    acc0[t] = (f32x4){0.f, 0.f, 0.f, 0.f};
    acc1[t] = (f32x4){0.f, 0.f, 0.f, 0.f};
  }

  short8 a6_0 = 0, a6_1 = 0;
  if (q == 0) { a6_0[0] = (short)f2bf(at0); a6_1[0] = (short)f2bf(at1); }

  MLP1_STEP(0, hs0a, hs1a)
  MLP1_STEP(1, hs0b, hs1b)
  MLP1_STEP(2, hd0a, hd1a)
  MLP1_STEP(3, hd0b, hd1b)
  MLP1_STEP(4, absdiff8(hs0a, hd0a), absdiff8(hs1a, hd1a))
  MLP1_STEP(5, absdiff8(hs0b, hd0b), absdiff8(hs1b, hd1b))
  MLP1_STEP(6, a6_0, a6_1)

  ushort* myt1 = t1s[w];
  auto do_group = [&](f32x4* acc, int g) {
#pragma unroll
    for (int t = 0; t < 8; t++)
#pragma unroll
      for (int r = 0; r < 4; r++)
        myt1[(q * 4 + r) * 136 + t * 16 + nn] = f2bf(lrelu(acc[t][r] + bm1v[t]));
    f32x4 acc2[4];
#pragma unroll
    for (int t = 0; t < 4; t++) acc2[t] = (f32x4){0.f, 0.f, 0.f, 0.f};
#pragma unroll
    for (int c2 = 0; c2 < 4; c2++) {
      short8 a = *(short8*)&myt1[nn * 136 + c2 * 32 + q * 8];
#pragma unroll
      for (int t = 0; t < 4; t++) {
        short8 b = *(const short8*)(W2f + ((size_t)(c2 * 4 + t) * 64 + lane) * 8);
        acc2[t] = __builtin_amdgcn_mfma_f32_16x16x32_bf16(a, b, acc2[t], 0, 0, 0);
      }
    }
#pragma unroll
    for (int r = 0; r < 4; r++) {
      float sum = 0.f;
#pragma unroll
      for (int t = 0; t < 4; t++) sum += lrelu(acc2[t][r] + bm2v[t]) * w3v[t];
      sum += __shfl_xor(sum, 1);
      sum += __shfl_xor(sum, 2);
      sum += __shfl_xor(sum, 4);
      sum += __shfl_xor(sum, 8);
      if (nn == 0) out[base + g * 16 + q * 4 + r] = sum + bm3v;
    }
  };
  do_group(acc0, 0);
  do_group(acc1, 1);
}

// ---------------- orchestration ----------------
extern "C" void kernel_launch(void* const* d_in, const int* in_sizes, int n_in,
                              void* d_out, int out_size, void* d_ws, size_t ws_size,
                              hipStream_t stream) {
  const float* x    = (const float*)d_in[0];
  const int*   ei   = (const int*)d_in[1];
  const float* eatt = (const float*)d_in[2];
  const float* W0 = (const float*)d_in[3];
  const float* as0 = (const float*)d_in[4];
  const float* ad0 = (const float*)d_in[5];
  const float* b0 = (const float*)d_in[6];
  const float* W1 = (const float*)d_in[7];
  const float* as1 = (const float*)d_in[8];
  const float* ad1 = (const float*)d_in[9];
  const float* b1 = (const float*)d_in[10];
  const float* W2 = (const float*)d_in[11];
  const float* as2 = (const float*)d_in[12];
  const float* ad2 = (const float*)d_in[13];
  const float* b2 = (const float*)d_in[14];
  const float* g0 = (const float*)d_in[15];
  const float* be0 = (const float*)d_in[16];
  const float* g1 = (const float*)d_in[17];
  const float* be1 = (const float*)d_in[18];
  const float* g2 = (const float*)d_in[19];
  const float* be2 = (const float*)d_in[20];
  const float* Wm1 = (const float*)d_in[21];
  const float* bm1 = (const float*)d_in[22];
  const float* Wm2 = (const float*)d_in[23];
  const float* bm2 = (const float*)d_in[24];
  const float* Wm3 = (const float*)d_in[25];
  const float* bm3 = (const float*)d_in[26];
  const int* src = ei;
  const int* dst = ei + Ee;
  float* out = (float*)d_out;

  // ---- workspace layout ----
  char* w = (char*)d_ws;
  ushort* xb   = (ushort*)w;                                  // Npad*128 bf16 (layer-0 A)
  ushort* hB   = (ushort*)(w + (size_t)Npad * 256 * 4);       // node-major [Npad][256] bf16
  ushort* aggb = (ushort*)(w + (size_t)Npad * 256 * 6);       // Npad*256 bf16 (post-gather/BN A)
  float*  h2   = (float*)aggb;                                // alias (layer-2 only): Nn*64 fp32
  ushort* hb2  = (ushort*)(w + (size_t)Npad * 256 * 6 + (size_t)Nn * 64 * 4);  // Nn*64 bf16
  float*  asrc = (float*)(w + (size_t)Npad * 256 * 8);        // Npad*4
  float*  adst = asrc + (size_t)Npad * 4;                     // Npad*4
  float*  stats = adst + (size_t)Npad * 4;                    // 512
  int* deg      = (int*)(stats + 512);                        // Nn
  int* rowstart = deg + Nn;                                   // Nn+16
  int* cursor   = rowstart + Nn + 16;                         // Nn
  int* elist    = cursor + Nn;                                // Ee+Nn
  ushort* W0f  = (ushort*)(elist + Ee + Nn);                  // 32768
  ushort* W1gf = W0f + 32768;                                 // 65536
  ushort* W2gf = W1gf + 65536;                                // 65536
  ushort* eW1f = W2gf + 65536;                                // 28672
  ushort* eW2f = eW1f + 28672;                                // 8192

  // ---- CSR build (once; edge_index identical for all 3 layers) ----
  filli_kernel<<<(Nn + 255) / 256, 256, 0, stream>>>(deg, 1, Nn);  // self loops
  hist_kernel<<<(Ee + 255) / 256, 256, 0, stream>>>(dst, deg);
  scan_kernel<<<1, 1024, 0, stream>>>(deg, rowstart, cursor);
  elist_fill_kernel<<<(Ee + Nn + 255) / 256, 256, 0, stream>>>(src, dst, cursor, elist);

  // ---- weight swizzles (once) ----
  wfrag_kernel<<<(32768 + 255) / 256, 256, 0, stream>>>(W0, W0f, FIN);
  wfrag_kernel<<<(65536 + 255) / 256, 256, 0, stream>>>(W1, W1gf, HD);
  wfrag_kernel<<<(65536 + 255) / 256, 256, 0, stream>>>(W2, W2gf, HD);
  w1frag_kernel<<<(7 * 8 * 64 * 8 + 255) / 256, 256, 0, stream>>>(Wm1, eW1f);
  w2frag_kernel<<<(4 * 4 * 64 * 8 + 255) / 256, 256, 0, stream>>>(Wm2, eW2f);

  auto gat = [&](const ushort* Ab, const ushort* Wf, int K, const float* a_s,
                 const float* a_d, const float* bias, bool concat) {
    gemm_mfma_kernel<<<dim3(Npad / 128, 2), 256, 0, stream>>>(Ab, Wf, hB, K, a_s, a_d,
                                                              asrc, adst);
    gat_gather_kernel<<<Nn / 4, 256, 0, stream>>>(elist, rowstart, hB, asrc, adst, bias,
                                                  aggb, h2, concat ? 1 : 0);
  };

  // Layer 0
  cvt_bf16_kernel<<<(Nn * FIN + 255) / 256, 256, 0, stream>>>(x, xb, Nn * FIN);
  gat(xb, W0f, FIN, as0, ad0, b0, true);
  fill_kernel<<<2, 256, 0, stream>>>(stats, 0.f, 512);
  bn_stats_bf16_kernel<<<(Nn + 511) / 512, 256, 0, stream>>>(aggb, stats, Nn, HD);
  bn_apply_inplace_kernel<<<(Nn * HD + 255) / 256, 256, 0, stream>>>(aggb, stats, g0, be0, HD);
  // Layer 1
  gat(aggb, W1gf, HD, as1, ad1, b1, true);
  fill_kernel<<<2, 256, 0, stream>>>(stats, 0.f, 512);
  bn_stats_bf16_kernel<<<(Nn + 511) / 512, 256, 0, stream>>>(aggb, stats, Nn, HD);
  bn_apply_inplace_kernel<<<(Nn * HD + 255) / 256, 256, 0, stream>>>(aggb, stats, g1, be1, HD);
  // Layer 2 (concat=False; head-mean + b2 fused into gather -> h2 fp32)
  gat(aggb, W2gf, HD, as2, ad2, b2, false);
  fill_kernel<<<1, 256, 0, stream>>>(stats, 0.f, 128);
  bn_stats_kernel<<<(Nn + 511) / 512, 256, 0, stream>>>(h2, stats, Nn, HIDd);
  bn_apply_bf16_kernel<<<(Nn * HIDd + 255) / 256, 256, 0, stream>>>(h2, stats, g2, be2, hb2,
                                                                    HIDd);
  // ---- Edge MLP (MFMA bf16) ----
  edge_mlp_mfma_kernel<<<Ee / 128, 256, 0, stream>>>(hb2, src, dst, eatt, eW1f, eW2f, bm1, bm2,
                                                     Wm3, bm3, out);
}